// Round 8
// baseline (192.748 us; speedup 1.0000x reference)
//
#include <hip/hip_runtime.h>
#include <hip/hip_bf16.h>
#include <stdint.h>
#include <stddef.h>

typedef __bf16 bf16;
typedef __attribute__((ext_vector_type(8))) __bf16 bf16x8;
typedef __attribute__((ext_vector_type(4))) __bf16 bf16x4;
typedef __attribute__((ext_vector_type(2))) __bf16 bf16x2;
typedef __attribute__((ext_vector_type(4))) float f32x4;

#define MFMA16(a, b, c) __builtin_amdgcn_mfma_f32_16x16x32_bf16(a, b, c, 0, 0, 0)

#define BB 2
#define SEQ 2048
#define FDIM 1024
#define NH 16
#define HD 64
#define M_TOK 4096   /* BB*SEQ */
#define N_QKV 3072   /* 3*FDIM */

#define CSC 0.04508422f  /* (1/32) * log2(e) — folded into Wq/bq */

// async global->LDS, 16B per lane; LDS dest is wave-uniform base + lane*16
__device__ __forceinline__ void gll16(const bf16* g, bf16* l) {
    __builtin_amdgcn_global_load_lds(
        (const __attribute__((address_space(1))) void*)g,
        (__attribute__((address_space(3))) void*)l, 16, 0, 0);
}

// fast f32 -> bf16 (round-to-nearest; 2 VALU ops)
__device__ __forceinline__ bf16 pack_bf16(float f) {
    uint32_t u = __builtin_bit_cast(uint32_t, f);
    uint16_t h = (uint16_t)((u + 0x8000u) >> 16);
    return __builtin_bit_cast(bf16, h);
}

// pack two f32 -> one dword of two bf16 (lo=a, hi=b)
__device__ __forceinline__ uint32_t pk2(float a, float b) {
#if __has_builtin(__builtin_amdgcn_cvt_pk_bf16_f32)
    bf16x2 t = __builtin_amdgcn_cvt_pk_bf16_f32(a, b);
    return __builtin_bit_cast(uint32_t, t);
#else
    uint32_t ua = __builtin_bit_cast(uint32_t, a) + 0x8000u;
    uint32_t ub = __builtin_bit_cast(uint32_t, b) + 0x8000u;
    return __builtin_amdgcn_perm(ub, ua, 0x07060302);
#endif
}

// ---------------------------------------------------------------------------
// fp32 -> bf16 conversion; Wq/bq pre-scaled by CSC.
// ---------------------------------------------------------------------------
__global__ __launch_bounds__(256) void convert_k(
    const float* __restrict__ x,
    const float* __restrict__ Wq, const float* __restrict__ bq,
    const float* __restrict__ Wk, const float* __restrict__ bk,
    const float* __restrict__ Wv, const float* __restrict__ bv,
    const float* __restrict__ Wo,
    bf16* __restrict__ xb, bf16* __restrict__ Wcat, bf16* __restrict__ Wob,
    float* __restrict__ bcat)
{
    const int tid = blockIdx.x * blockDim.x + threadIdx.x;
    const int nt = gridDim.x * blockDim.x;
    const int NX4 = M_TOK * FDIM / 4;
    const int NW4 = FDIM * FDIM / 4;

    for (int i = tid; i < NX4; i += nt) {
        float4 v = ((const float4*)x)[i];
        bf16x4 o; o[0] = (bf16)v.x; o[1] = (bf16)v.y; o[2] = (bf16)v.z; o[3] = (bf16)v.w;
        ((bf16x4*)xb)[i] = o;
    }
    for (int i = tid; i < NW4; i += nt) {
        float4 v = ((const float4*)Wq)[i];
        bf16x4 o;
        o[0] = (bf16)(v.x * CSC); o[1] = (bf16)(v.y * CSC);
        o[2] = (bf16)(v.z * CSC); o[3] = (bf16)(v.w * CSC);
        ((bf16x4*)Wcat)[i] = o;
        v = ((const float4*)Wk)[i];
        o[0] = (bf16)v.x; o[1] = (bf16)v.y; o[2] = (bf16)v.z; o[3] = (bf16)v.w;
        ((bf16x4*)Wcat)[NW4 + i] = o;
        v = ((const float4*)Wv)[i];
        o[0] = (bf16)v.x; o[1] = (bf16)v.y; o[2] = (bf16)v.z; o[3] = (bf16)v.w;
        ((bf16x4*)Wcat)[2 * NW4 + i] = o;
        v = ((const float4*)Wo)[i];
        o[0] = (bf16)v.x; o[1] = (bf16)v.y; o[2] = (bf16)v.z; o[3] = (bf16)v.w;
        ((bf16x4*)Wob)[i] = o;
    }
    for (int i = tid; i < FDIM; i += nt) {
        bcat[i] = bq[i] * CSC;
        bcat[FDIM + i] = bk[i];
        bcat[2 * FDIM + i] = bv[i];
    }
}

// ---------------------------------------------------------------------------
// C[M,N] = A[M,K] @ B[N,K]^T + bias[N].  MT x 128 tile (MT=128 or 64),
// double-buffered global_load_lds staging, one barrier per K-step.
// MT=128 + VtOut: V third (n0>=2048) written transposed+j-permuted to
// VtOut[bh][d][j'] (perm per 64-token tile) for attn's b128 V-frag reads.
// ---------------------------------------------------------------------------
template<int MT>
__global__ __launch_bounds__(256) void gemm_bt(
    const bf16* __restrict__ A,    // M x K
    const bf16* __restrict__ Bw,   // N x K
    const float* __restrict__ bias,// N
    bf16* __restrict__ Cb,         // bf16 out (or null)
    float* __restrict__ Cf,        // fp32 out (or null)
    bf16* __restrict__ VtOut,      // optional transposed-V output (MT=128)
    int M, int N, int K)
{
    constexpr int RI = MT / 32;    // row frags per wave
    __shared__ __align__(16) bf16 As[2][MT * 32];
    __shared__ __align__(16) bf16 Bs[2][128 * 32];

    const int tid = threadIdx.x;
    const int lane = tid & 63;
    const int wave = tid >> 6;
    const int m0 = blockIdx.y * MT;
    const int n0 = blockIdx.x * 128;
    const int wm = (wave >> 1) * (MT / 2);
    const int wn = (wave & 1) * 64;
    const int lrow = lane & 15;
    const int lk8 = (lane >> 4) * 8;

    f32x4 acc[RI][4] = {};

    const int srow = wave * 16 + (lane >> 2);
    const int scol = (lane & 3) * 8;
    const bf16* Ag = A + (size_t)(m0 + srow) * K + scol;
    const bf16* Bg = Bw + (size_t)(n0 + srow) * K + scol;
    const int wo = (wave * 16) * 32;

    // prologue: stage k-tile 0 into buffer 0
    gll16(Ag, &As[0][wo]);
    if (MT == 128) gll16(Ag + (size_t)64 * K, &As[0][wo + 2048]);
    gll16(Bg, &Bs[0][wo]);
    gll16(Bg + (size_t)64 * K, &Bs[0][wo + 2048]);

    for (int k0 = 0, it = 0; k0 < K; k0 += 32, ++it) {
        const int cur = it & 1;
        __syncthreads();   // drains loads(it); all waves done reading buf cur^1

        if (k0 + 32 < K) {
            const int nxt = cur ^ 1;
            gll16(Ag + k0 + 32, &As[nxt][wo]);
            if (MT == 128) gll16(Ag + (size_t)64 * K + k0 + 32, &As[nxt][wo + 2048]);
            gll16(Bg + k0 + 32, &Bs[nxt][wo]);
            gll16(Bg + (size_t)64 * K + k0 + 32, &Bs[nxt][wo + 2048]);
        }

        bf16x8 af[RI], bfr[4];
#pragma unroll
        for (int s = 0; s < RI; ++s)
            af[s] = *(const bf16x8*)&As[cur][(wm + s * 16 + lrow) * 32 + lk8];
#pragma unroll
        for (int s = 0; s < 4; ++s)
            bfr[s] = *(const bf16x8*)&Bs[cur][(wn + s * 16 + lrow) * 32 + lk8];
#pragma unroll
        for (int i = 0; i < RI; ++i)
#pragma unroll
            for (int j = 0; j < 4; ++j)
                acc[i][j] = MFMA16(af[i], bfr[j], acc[i][j]);
    }

    // epilogue: C/D layout col=lane&15, row=(lane>>4)*4+reg  [m89/m91]
    const int r0 = (lane >> 4) * 4;
    if (MT == 128 && VtOut && n0 >= 2048) {
        const int bql = (m0 >> 11);            // batch (block-uniform)
#pragma unroll
        for (int i = 0; i < RI; ++i) {
#pragma unroll
            for (int j = 0; j < 4; ++j) {
                const int col = n0 + wn + j * 16 + lrow;   // 2048..3071
                const float bsv = bias[col];
                const int vh = col - 2048;                 // h*64 + d
                const int row = m0 + wm + i * 16 + r0;     // token of reg 0
                const int jj = row & (SEQ - 1);
                const int g = jj & 63;
                const int jj2 = (jj & ~63) | ((g >> 5) << 5)
                              | (((g >> 2) & 3) << 3) | (((g >> 4) & 1) << 2);
                bf16x4 vv;
#pragma unroll
                for (int r = 0; r < 4; ++r)
                    vv[r] = pack_bf16(acc[i][j][r] + bsv);
                *(bf16x4*)&VtOut[((size_t)bql * 16 * 64 + vh) * SEQ + jj2] = vv;
            }
        }
        return;
    }
#pragma unroll
    for (int i = 0; i < RI; ++i) {
#pragma unroll
        for (int j = 0; j < 4; ++j) {
            const int col = n0 + wn + j * 16 + lrow;
            const float bsv = bias[col];
#pragma unroll
            for (int r = 0; r < 4; ++r) {
                const int row = m0 + wm + i * 16 + r0 + r;
                const float v = acc[i][j][r] + bsv;
                if (Cb) Cb[(size_t)row * N + col] = pack_bf16(v);
                else    Cf[(size_t)row * N + col] = v;
            }
        }
    }
}

// ---------------------------------------------------------------------------
// Flash attention v8: 128 threads = 2 waves; each wave owns 64 Q rows (4
// q-tiles) so every K/V fragment read from LDS feeds 4 MFMAs instead of 2 —
// halves LDS read traffic per FLOP (the R7 bottleneck).  128-j tiles double-
// buffered, one barrier per tile; wave 0 stages K, wave 1 stages V.
// XCD swizzle keeps all q-blocks of one (b,h) on one XCD (K/V L2-resident).
// S^T = MFMA(A=K, B=Q); P^T = exp2(S^T) packed in-register into K=32 B-frags
// (jn-pair perm pi baked into Vt's column order); PV + row-sums via MFMA.
// ---------------------------------------------------------------------------
__global__ __launch_bounds__(128) void attn_k(
    const bf16* __restrict__ QKV,  // M_TOK x 3072 : [Q | K | (unused V)]
    const bf16* __restrict__ Vt,   // [bh*64 + d][SEQ], j-permuted per 64-tile
    bf16* __restrict__ O)          // M_TOK x 1024
{
    const int bx = blockIdx.x;
    const int bh = (bx & 7) + 8 * ((bx >> 3) & 3);   // same bh -> same XCD (%8)
    const int qblk = bx >> 5;
    const int b = bh >> 4;
    const int h = bh & 15;
    const int lane = threadIdx.x & 63;
    const int wave = threadIdx.x >> 6;
    const int lrow = lane & 15;
    const int quad = lane >> 4;
    const int lk8 = quad * 8;

    __shared__ __align__(16) bf16 Ks[2][2][128 * 32];  // [stage][ksplit][j<128]
    __shared__ __align__(16) bf16 Vs[2][4][64 * 32];   // [stage][j-32-chunk][d<64]

    const size_t base = (size_t)b * SEQ * N_QKV;
    const bf16* Qp = QKV + base + h * HD;
    const bf16* Kp = QKV + base + FDIM + h * HD;
    const bf16* Vtp = Vt + (size_t)bh * HD * SEQ;

    const int qr0 = qblk * 128 + wave * 64;

    bf16x8 qf[4][2];
#pragma unroll
    for (int qt = 0; qt < 4; ++qt)
#pragma unroll
        for (int ks = 0; ks < 2; ++ks)
            qf[qt][ks] = *(const bf16x8*)(Qp + (size_t)(qr0 + qt * 16 + lrow) * N_QKV
                                          + ks * 32 + lk8);

    bf16x8 ones8;
#pragma unroll
    for (int e = 0; e < 8; ++e) ones8[e] = (bf16)1.0f;

    const f32x4 zf = {0.f, 0.f, 0.f, 0.f};   // persistent zero C operand

    f32x4 o[4][4] = {};   // O^T frags: [qt][df]
    f32x4 o4[4] = {};     // row sums (replicated over rows)

    // staging: wave 0 -> K (16 KB = 16 gll16), wave 1 -> V (16 KB)
    const int sr = lane >> 2;            // row within 16-row chunk
    const int sc = (lane & 3) * 8;       // col segment
    const bf16* kg = Kp + (size_t)sr * N_QKV + sc;   // + i*16*N_QKV + ks*32
    const bf16* vg = Vtp + (size_t)sr * SEQ + sc;    // + i*16*SEQ + p*32

    // prologue: stage j-tile 0 (128 j) into buffer 0
    if (wave == 0) {
#pragma unroll
        for (int i = 0; i < 8; ++i) {
            gll16(kg + (size_t)i * 16 * N_QKV, &Ks[0][0][i * 16 * 32]);
            gll16(kg + (size_t)i * 16 * N_QKV + 32, &Ks[0][1][i * 16 * 32]);
        }
    } else {
#pragma unroll
        for (int p = 0; p < 4; ++p)
#pragma unroll
            for (int i = 0; i < 4; ++i)
                gll16(vg + (size_t)i * 16 * SEQ + p * 32, &Vs[0][p][i * 16 * 32]);
    }
    kg += (size_t)128 * N_QKV;
    vg += 128;

    for (int jt = 0; jt < SEQ / 128; ++jt) {
        const int cur = jt & 1;
        __syncthreads();   // drains loads(jt); all waves done reading buf cur^1

        if (jt + 1 < SEQ / 128) {
            const int nxt = cur ^ 1;
            if (wave == 0) {
#pragma unroll
                for (int i = 0; i < 8; ++i) {
                    gll16(kg + (size_t)i * 16 * N_QKV, &Ks[nxt][0][i * 16 * 32]);
                    gll16(kg + (size_t)i * 16 * N_QKV + 32, &Ks[nxt][1][i * 16 * 32]);
                }
            } else {
#pragma unroll
                for (int p = 0; p < 4; ++p)
#pragma unroll
                    for (int i = 0; i < 4; ++i)
                        gll16(vg + (size_t)i * 16 * SEQ + p * 32, &Vs[nxt][p][i * 16 * 32]);
            }
            kg += (size_t)128 * N_QKV;
            vg += 128;
        }

        // process 128 j in 4 chunks of 32 (jn pair per chunk)
#pragma unroll
        for (int p = 0; p < 4; ++p) {
            f32x4 Sp[2][4];   // [m=jn&1][qt]
#pragma unroll
            for (int m = 0; m < 2; ++m) {
                const int jn = 2 * p + m;
                bf16x8 kb0 = *(const bf16x8*)&Ks[cur][0][(jn * 16 + lrow) * 32 + lk8];
                bf16x8 kb1 = *(const bf16x8*)&Ks[cur][1][(jn * 16 + lrow) * 32 + lk8];
#pragma unroll
                for (int qt = 0; qt < 4; ++qt) {
                    Sp[m][qt] = MFMA16(kb0, qf[qt][0], zf);
                    Sp[m][qt] = MFMA16(kb1, qf[qt][1], Sp[m][qt]);
                }
            }

            // P^T = exp2(S^T) packed into K=32 B-frags (perm pi, matches Vt)
            union { bf16x8 v; uint32_t d[4]; } pb[4];
#pragma unroll
            for (int qt = 0; qt < 4; ++qt) {
                const f32x4 s0 = Sp[0][qt];
                const f32x4 s1 = Sp[1][qt];
                pb[qt].d[0] = pk2(__builtin_amdgcn_exp2f(s0[0]),
                                  __builtin_amdgcn_exp2f(s0[1]));
                pb[qt].d[1] = pk2(__builtin_amdgcn_exp2f(s0[2]),
                                  __builtin_amdgcn_exp2f(s0[3]));
                pb[qt].d[2] = pk2(__builtin_amdgcn_exp2f(s1[0]),
                                  __builtin_amdgcn_exp2f(s1[1]));
                pb[qt].d[3] = pk2(__builtin_amdgcn_exp2f(s1[2]),
                                  __builtin_amdgcn_exp2f(s1[3]));
                o4[qt] = MFMA16(ones8, pb[qt].v, o4[qt]);
            }

#pragma unroll
            for (int df = 0; df < 4; ++df) {
                bf16x8 vA = *(const bf16x8*)&Vs[cur][p][(df * 16 + lrow) * 32 + lk8];
#pragma unroll
                for (int qt = 0; qt < 4; ++qt)
                    o[qt][df] = MFMA16(vA, pb[qt].v, o[qt][df]);
            }
        }
    }

    // epilogue: O^T frag: d = df*16 + quad*4 + r, q = lane&15
#pragma unroll
    for (int qt = 0; qt < 4; ++qt) {
        const float inv = 1.0f / o4[qt][0];
        const int q = qr0 + qt * 16 + lrow;
#pragma unroll
        for (int df = 0; df < 4; ++df) {
            bf16x4 vv;
#pragma unroll
            for (int r = 0; r < 4; ++r)
                vv[r] = pack_bf16(o[qt][df][r] * inv);
            *(bf16x4*)&O[(size_t)(b * SEQ + q) * FDIM + h * HD + df * 16 + quad * 4] = vv;
        }
    }
}

// ---------------------------------------------------------------------------
extern "C" void kernel_launch(void* const* d_in, const int* in_sizes, int n_in,
                              void* d_out, int out_size, void* d_ws, size_t ws_size,
                              hipStream_t stream) {
    (void)in_sizes; (void)n_in; (void)out_size; (void)ws_size;
    const float* x  = (const float*)d_in[0];
    const float* Wq = (const float*)d_in[1];
    const float* bq = (const float*)d_in[2];
    const float* Wk = (const float*)d_in[3];
    const float* bk = (const float*)d_in[4];
    const float* Wv = (const float*)d_in[5];
    const float* bv = (const float*)d_in[6];
    const float* Wo = (const float*)d_in[7];
    const float* bo = (const float*)d_in[8];
    float* out = (float*)d_out;

    char* ws = (char*)d_ws;
    bf16* xb    = (bf16*)(ws);                // 8 MB; reused as Ob after GEMM1
    bf16* Wcat  = (bf16*)(ws + 8388608);      // 6 MB
    bf16* Wob   = (bf16*)(ws + 14680064);     // 2 MB
    float* bcat = (float*)(ws + 16777216);    // 12 KB
    bf16* QKV   = (bf16*)(ws + 16789504);     // 24 MB (V third unused)
    bf16* Vt    = (bf16*)(ws + 41955328);     // 8 MB, j-permuted layout
    bf16* Ob    = xb;                         // x no longer needed after GEMM1

    convert_k<<<dim3(1024), dim3(256), 0, stream>>>(x, Wq, bq, Wk, bk, Wv, bv, Wo,
                                                    xb, Wcat, Wob, bcat);
    gemm_bt<128><<<dim3(N_QKV / 128, M_TOK / 128), dim3(256), 0, stream>>>(
        xb, Wcat, bcat, QKV, nullptr, Vt, M_TOK, N_QKV, FDIM);
    attn_k<<<dim3((SEQ / 128) * BB * NH), dim3(128), 0, stream>>>(QKV, Vt, Ob);
    gemm_bt<64><<<dim3(FDIM / 128, M_TOK / 64), dim3(256), 0, stream>>>(
        Ob, Wob, bo, nullptr, out, nullptr, M_TOK, FDIM, FDIM);
}